// Round 1
// baseline (643.879 us; speedup 1.0000x reference)
//
#include <hip/hip_runtime.h>
#include <math.h>

#define BATCH 16
#define SEQ 64
#define NKEY 196
#define HIDDEN 1024
#define ATT_FEAT 2048
#define EMBED 512

// ---------------------------------------------------------------------------
// Generic tiled f32 GEMM: C[M,N] = A[M,K] @ B[K,N] (+ bias[N])
// 64x64 tile, BK=16, 256 threads, 4x4 microtile per thread.
// M,N multiples of 64; K multiple of 16 (true for all our shapes).
// ---------------------------------------------------------------------------
#define GBM 64
#define GBN 64
#define GBK 16
__global__ __launch_bounds__(256) void gemm_bias_f32(
    const float* __restrict__ A, const float* __restrict__ Bm,
    const float* __restrict__ bias, float* __restrict__ C,
    int M, int N, int K)
{
    __shared__ float As[GBK][GBM + 1];  // stored transposed
    __shared__ float Bs[GBK][GBN + 1];
    const int tid = threadIdx.x;
    const int tx = tid & 15;        // 0..15 -> 4 cols each
    const int ty = tid >> 4;        // 0..15 -> 4 rows each
    const int row0 = blockIdx.y * GBM;
    const int col0 = blockIdx.x * GBN;

    float acc[4][4] = {};

    for (int k0 = 0; k0 < K; k0 += GBK) {
        // A tile: 64 rows x 16 k -> store transposed As[k][row]
        for (int i = tid; i < GBM * GBK; i += 256) {
            int r = i >> 4, c = i & 15;
            As[c][r] = A[(size_t)(row0 + r) * K + k0 + c];
        }
        // B tile: 16 k x 64 cols
        for (int i = tid; i < GBK * GBN; i += 256) {
            int r = i >> 6, c = i & 63;
            Bs[r][c] = Bm[(size_t)(k0 + r) * N + col0 + c];
        }
        __syncthreads();
        #pragma unroll
        for (int kk = 0; kk < GBK; ++kk) {
            float a[4], b[4];
            #pragma unroll
            for (int j = 0; j < 4; ++j) a[j] = As[kk][ty * 4 + j];
            #pragma unroll
            for (int j = 0; j < 4; ++j) b[j] = Bs[kk][tx * 4 + j];
            #pragma unroll
            for (int i = 0; i < 4; ++i)
                #pragma unroll
                for (int j = 0; j < 4; ++j)
                    acc[i][j] += a[i] * b[j];
        }
        __syncthreads();
    }

    #pragma unroll
    for (int i = 0; i < 4; ++i) {
        int r = row0 + ty * 4 + i;
        #pragma unroll
        for (int j = 0; j < 4; ++j) {
            int c = col0 + tx * 4 + j;
            float v = acc[i][j];
            if (bias) v += bias[c];
            C[(size_t)r * N + c] = v;
        }
    }
}

// ---------------------------------------------------------------------------
// scores[b,s,n] = sum_e tanh(Wh[b,s,e] + Uv[b,n,e]) * w[e]   (b folded in Uv)
// then mask==0 -> -1e9. Tile: 16 s x 16 n per block, E chunked by 128 in LDS.
// ---------------------------------------------------------------------------
__global__ __launch_bounds__(256) void scores_kernel(
    const float* __restrict__ Wh, const float* __restrict__ Uv,
    const float* __restrict__ wvec, const int* __restrict__ mask,
    float* __restrict__ scores)
{
    const int n0 = blockIdx.x * 16;   // 13 tiles (196)
    const int s0 = blockIdx.y * 16;   // 4 tiles (64)
    const int b  = blockIdx.z;
    const int tid = threadIdx.x;
    const int tx = tid & 15;          // n within tile
    const int ty = tid >> 4;          // s within tile

    __shared__ float whs[16][129];
    __shared__ float uvs[16][129];
    __shared__ float wl[128];

    float acc = 0.f;
    for (int e0 = 0; e0 < EMBED; e0 += 128) {
        for (int i = tid; i < 16 * 128; i += 256) {
            int r = i >> 7, c = i & 127;
            whs[r][c] = Wh[(size_t)(b * SEQ + s0 + r) * EMBED + e0 + c];
        }
        for (int i = tid; i < 16 * 128; i += 256) {
            int r = i >> 7, c = i & 127;
            int n = n0 + r;
            uvs[r][c] = (n < NKEY) ? Uv[(size_t)(b * NKEY + n) * EMBED + e0 + c] : 0.f;
        }
        if (tid < 128) wl[tid] = wvec[e0 + tid];
        __syncthreads();
        #pragma unroll 16
        for (int e = 0; e < 128; ++e) {
            float x = whs[ty][e] + uvs[tx][e];
            float ax = fabsf(x);
            float t = __expf(-2.f * ax);                  // exp(-2|x|)
            float th = __fdividef(1.f - t, 1.f + t);      // tanh(|x|)
            th = (x < 0.f) ? -th : th;
            acc += th * wl[e];
        }
        __syncthreads();
    }

    const int n = n0 + tx;
    const int s = s0 + ty;
    if (n < NKEY) {
        float v = (mask[b * NKEY + n] == 0) ? -1e9f : acc;
        scores[(size_t)(b * SEQ + s) * NKEY + n] = v;
    }
}

// ---------------------------------------------------------------------------
// In-place row softmax over N=196. One wave (64 lanes) per row, 4 elems/lane.
// ---------------------------------------------------------------------------
__global__ __launch_bounds__(64) void softmax_kernel(float* __restrict__ sw)
{
    const int row = blockIdx.x;        // b*SEQ + s
    const int lane = threadIdx.x;
    float v[4];
    float mx = -INFINITY;
    #pragma unroll
    for (int k = 0; k < 4; ++k) {
        int n = lane + 64 * k;
        v[k] = (n < NKEY) ? sw[(size_t)row * NKEY + n] : -INFINITY;
        mx = fmaxf(mx, v[k]);
    }
    #pragma unroll
    for (int off = 32; off; off >>= 1) mx = fmaxf(mx, __shfl_xor(mx, off));
    float sum = 0.f;
    #pragma unroll
    for (int k = 0; k < 4; ++k) {
        v[k] = __expf(v[k] - mx);
        if (lane + 64 * k < NKEY) sum += v[k];
    }
    #pragma unroll
    for (int off = 32; off; off >>= 1) sum += __shfl_xor(sum, off);
    const float inv = __fdividef(1.f, sum);
    #pragma unroll
    for (int k = 0; k < 4; ++k) {
        int n = lane + 64 * k;
        if (n < NKEY) sw[(size_t)row * NKEY + n] = v[k] * inv;
    }
}

// ---------------------------------------------------------------------------
// attn[b,s,f] = sum_n weights[b,s,n] * feats[b,n,f]
// Block: 256 consecutive f-columns x 8 s-rows; weights tile in LDS.
// Grid: (F/256=8, SEQ/8=8, B=16)
// ---------------------------------------------------------------------------
__global__ __launch_bounds__(256) void attn_kernel(
    const float* __restrict__ weights, const float* __restrict__ feats,
    float* __restrict__ out)
{
    const int col = blockIdx.x * 256 + threadIdx.x;
    const int s0  = blockIdx.y * 8;
    const int b   = blockIdx.z;

    __shared__ float wl[8][NKEY];
    for (int i = threadIdx.x; i < 8 * NKEY; i += 256) {
        int s = i / NKEY, n = i % NKEY;
        wl[s][n] = weights[(size_t)(b * SEQ + s0 + s) * NKEY + n];
    }
    __syncthreads();

    float acc[8] = {};
    for (int n = 0; n < NKEY; ++n) {
        float f = feats[(size_t)(b * NKEY + n) * ATT_FEAT + col];
        #pragma unroll
        for (int s = 0; s < 8; ++s) acc[s] += wl[s][n] * f;
    }
    #pragma unroll
    for (int s = 0; s < 8; ++s)
        out[(size_t)(b * SEQ + s0 + s) * ATT_FEAT + col] = acc[s];
}

// ---------------------------------------------------------------------------
extern "C" void kernel_launch(void* const* d_in, const int* in_sizes, int n_in,
                              void* d_out, int out_size, void* d_ws, size_t ws_size,
                              hipStream_t stream)
{
    const float* hidden = (const float*)d_in[0];  // [B,S,H]
    const float* feats  = (const float*)d_in[1];  // [B,N,F]
    const int*   mask   = (const int*)  d_in[2];  // [B,N]
    const float* w_h    = (const float*)d_in[3];  // [H,E]
    const float* w_u    = (const float*)d_in[4];  // [F,E]
    const float* bvec   = (const float*)d_in[5];  // [E]
    const float* wvec   = (const float*)d_in[6];  // [E]

    float* out         = (float*)d_out;
    float* attn_out    = out;                                      // B*S*F
    float* weights_out = out + (size_t)BATCH * SEQ * ATT_FEAT;     // B*S*N

    float* Wh = (float*)d_ws;                          // B*S*E  (2 MB)
    float* Uv = Wh + (size_t)BATCH * SEQ * EMBED;      // B*N*E  (6.4 MB)

    // K1: Wh = hidden @ w_h        [1024,1024] x [1024,512]
    gemm_bias_f32<<<dim3(EMBED / GBN, (BATCH * SEQ) / GBM), 256, 0, stream>>>(
        hidden, w_h, nullptr, Wh, BATCH * SEQ, EMBED, HIDDEN);

    // K2: Uv = feats @ w_u + b     [3136,2048] x [2048,512]
    gemm_bias_f32<<<dim3(EMBED / GBN, (BATCH * NKEY) / GBM), 256, 0, stream>>>(
        feats, w_u, bvec, Uv, BATCH * NKEY, EMBED, ATT_FEAT);

    // K3: scores (+mask) -> weights region of d_out
    scores_kernel<<<dim3((NKEY + 15) / 16, SEQ / 16, BATCH), 256, 0, stream>>>(
        Wh, Uv, wvec, mask, weights_out);

    // K4: softmax in place
    softmax_kernel<<<dim3(BATCH * SEQ), 64, 0, stream>>>(weights_out);

    // K5: attn_feats = weights @ feats
    attn_kernel<<<dim3(ATT_FEAT / 256, SEQ / 8, BATCH), 256, 0, stream>>>(
        weights_out, feats, attn_out);
}

// Round 2
// 252.475 us; speedup vs baseline: 2.5503x; 2.5503x over previous
//
#include <hip/hip_runtime.h>
#include <math.h>

#define BATCH 16
#define SEQ 64
#define NKEY 196
#define HIDDEN 1024
#define ATT_FEAT 2048
#define EMBED 512

using short8 = __attribute__((ext_vector_type(8))) short;
using f32x4  = __attribute__((ext_vector_type(4))) float;
using float4v = __attribute__((ext_vector_type(4))) float;

__device__ inline unsigned short f2bf(float x) {
    unsigned u = __builtin_bit_cast(unsigned, x);
    unsigned r = (u + 0x7FFFu + ((u >> 16) & 1u)) >> 16;
    return (unsigned short)r;
}
__device__ inline float bf2f(unsigned short h) {
    unsigned u = ((unsigned)h) << 16;
    return __builtin_bit_cast(float, u);
}

// swizzled byte offset within a [row][128B] LDS tile (T2 pattern)
__device__ inline int swz(int row, int kbyte) {
    return row * 128 + (kbyte ^ ((row & 7) << 4));
}

// ---------------------------------------------------------------------------
// Split-bf16 MFMA GEMM: C[M,N] = A[M,K] @ B[K,N] (+ bias), f32 in/out.
// Tile 64x64, BK=64. 256 threads = 4 waves, each wave owns a 32x32 quadrant
// (2x2 grid of 16x16x32 MFMA frags). 3 MFMA products: hi*hi + hi*lo + lo*hi.
// Requires M%64==0, N%64==0, K%64==0 (true for all our shapes).
// ---------------------------------------------------------------------------
__global__ __launch_bounds__(256) void gemm_mfma_split(
    const float* __restrict__ A, const float* __restrict__ Bm,
    const float* __restrict__ bias, float* __restrict__ C,
    int M, int N, int K)
{
    __shared__ __align__(16) unsigned short AsHi[64 * 64];
    __shared__ __align__(16) unsigned short AsLo[64 * 64];
    __shared__ __align__(16) unsigned short BsHi[64 * 64];
    __shared__ __align__(16) unsigned short BsLo[64 * 64];

    const int tid  = threadIdx.x;
    const int row0 = blockIdx.y * 64;
    const int col0 = blockIdx.x * 64;

    const int lane = tid & 63;
    const int w    = tid >> 6;
    const int wr   = w >> 1;          // wave row half (0/1)
    const int wc   = w & 1;           // wave col half (0/1)
    const int l15  = lane & 15;
    const int lg   = lane >> 4;       // 0..3

    // staging coords
    const int ar = tid >> 2;                 // A: row 0..63
    const int ac = (tid & 3) << 4;           // A: k chunk base (16 floats)
    const int bn = tid & 63;                 // B: col 0..63
    const int bk = (tid >> 6) << 4;          // B: k chunk base (16 floats)

    f32x4 acc[2][2] = {};

    char* AsHiB = (char*)AsHi;
    char* AsLoB = (char*)AsLo;
    char* BsHiB = (char*)BsHi;
    char* BsLoB = (char*)BsLo;

    for (int k0 = 0; k0 < K; k0 += 64) {
        // ---- stage A tile [64 rows][64 k] as hi/lo bf16, swizzled ----
        {
            const float* Ap = A + (size_t)(row0 + ar) * K + k0 + ac;
            float f[16];
            #pragma unroll
            for (int q = 0; q < 4; ++q) {
                float4v v = *(const float4v*)(Ap + q * 4);
                f[q * 4 + 0] = v.x; f[q * 4 + 1] = v.y;
                f[q * 4 + 2] = v.z; f[q * 4 + 3] = v.w;
            }
            short8 hi0, hi1, lo0, lo1;
            #pragma unroll
            for (int j = 0; j < 8; ++j) {
                unsigned short h = f2bf(f[j]);
                hi0[j] = (short)h;
                lo0[j] = (short)f2bf(f[j] - bf2f(h));
            }
            #pragma unroll
            for (int j = 0; j < 8; ++j) {
                unsigned short h = f2bf(f[8 + j]);
                hi1[j] = (short)h;
                lo1[j] = (short)f2bf(f[8 + j] - bf2f(h));
            }
            *(short8*)(AsHiB + swz(ar, ac * 2 + 0))  = hi0;
            *(short8*)(AsHiB + swz(ar, ac * 2 + 16)) = hi1;
            *(short8*)(AsLoB + swz(ar, ac * 2 + 0))  = lo0;
            *(short8*)(AsLoB + swz(ar, ac * 2 + 16)) = lo1;
        }
        // ---- stage B tile transposed: Bs[n][k], hi/lo bf16, swizzled ----
        {
            float f[16];
            #pragma unroll
            for (int j = 0; j < 16; ++j)
                f[j] = Bm[(size_t)(k0 + bk + j) * N + col0 + bn];
            short8 hi0, hi1, lo0, lo1;
            #pragma unroll
            for (int j = 0; j < 8; ++j) {
                unsigned short h = f2bf(f[j]);
                hi0[j] = (short)h;
                lo0[j] = (short)f2bf(f[j] - bf2f(h));
            }
            #pragma unroll
            for (int j = 0; j < 8; ++j) {
                unsigned short h = f2bf(f[8 + j]);
                hi1[j] = (short)h;
                lo1[j] = (short)f2bf(f[8 + j] - bf2f(h));
            }
            *(short8*)(BsHiB + swz(bn, bk * 2 + 0))  = hi0;
            *(short8*)(BsHiB + swz(bn, bk * 2 + 16)) = hi1;
            *(short8*)(BsLoB + swz(bn, bk * 2 + 0))  = lo0;
            *(short8*)(BsLoB + swz(bn, bk * 2 + 16)) = lo1;
        }
        __syncthreads();

        // ---- MFMA over the two 32-k halves ----
        #pragma unroll
        for (int ksub = 0; ksub < 2; ++ksub) {
            const int kb = ksub * 64 + lg * 16;   // byte offset of this lane's 16B
            short8 ah[2], al[2], bh[2], bl[2];
            #pragma unroll
            for (int m = 0; m < 2; ++m) {
                int off = swz(wr * 32 + m * 16 + l15, kb);
                ah[m] = *(const short8*)(AsHiB + off);
                al[m] = *(const short8*)(AsLoB + off);
            }
            #pragma unroll
            for (int n = 0; n < 2; ++n) {
                int off = swz(wc * 32 + n * 16 + l15, kb);
                bh[n] = *(const short8*)(BsHiB + off);
                bl[n] = *(const short8*)(BsLoB + off);
            }
            #pragma unroll
            for (int m = 0; m < 2; ++m)
                #pragma unroll
                for (int n = 0; n < 2; ++n) {
                    acc[m][n] = __builtin_amdgcn_mfma_f32_16x16x32_bf16(ah[m], bh[n], acc[m][n], 0, 0, 0);
                    acc[m][n] = __builtin_amdgcn_mfma_f32_16x16x32_bf16(ah[m], bl[n], acc[m][n], 0, 0, 0);
                    acc[m][n] = __builtin_amdgcn_mfma_f32_16x16x32_bf16(al[m], bh[n], acc[m][n], 0, 0, 0);
                }
        }
        __syncthreads();
    }

    // ---- epilogue: D[row=(lane>>4)*4+v][col=lane&15] per frag ----
    #pragma unroll
    for (int m = 0; m < 2; ++m)
        #pragma unroll
        for (int n = 0; n < 2; ++n)
            #pragma unroll
            for (int v = 0; v < 4; ++v) {
                int r = row0 + wr * 32 + m * 16 + lg * 4 + v;
                int c = col0 + wc * 32 + n * 16 + l15;
                float val = acc[m][n][v];
                if (bias) val += bias[c];
                C[(size_t)r * N + c] = val;
            }
}

// ---------------------------------------------------------------------------
// scores[b,s,n] = sum_e tanh(Wh[b,s,e] + Uv[b,n,e]) * w[e]
// then mask==0 -> -1e9. Tile: 16 s x 16 n per block, E chunked by 128 in LDS.
// ---------------------------------------------------------------------------
__global__ __launch_bounds__(256) void scores_kernel(
    const float* __restrict__ Wh, const float* __restrict__ Uv,
    const float* __restrict__ wvec, const int* __restrict__ mask,
    float* __restrict__ scores)
{
    const int n0 = blockIdx.x * 16;   // 13 tiles (196)
    const int s0 = blockIdx.y * 16;   // 4 tiles (64)
    const int b  = blockIdx.z;
    const int tid = threadIdx.x;
    const int tx = tid & 15;          // n within tile
    const int ty = tid >> 4;          // s within tile

    __shared__ float whs[16][129];
    __shared__ float uvs[16][129];
    __shared__ float wl[128];

    float acc = 0.f;
    for (int e0 = 0; e0 < EMBED; e0 += 128) {
        for (int i = tid; i < 16 * 128; i += 256) {
            int r = i >> 7, c = i & 127;
            whs[r][c] = Wh[(size_t)(b * SEQ + s0 + r) * EMBED + e0 + c];
        }
        for (int i = tid; i < 16 * 128; i += 256) {
            int r = i >> 7, c = i & 127;
            int n = n0 + r;
            uvs[r][c] = (n < NKEY) ? Uv[(size_t)(b * NKEY + n) * EMBED + e0 + c] : 0.f;
        }
        if (tid < 128) wl[tid] = wvec[e0 + tid];
        __syncthreads();
        #pragma unroll 16
        for (int e = 0; e < 128; ++e) {
            float x = whs[ty][e] + uvs[tx][e];
            float ax = fabsf(x);
            float t = __expf(-2.f * ax);                  // exp(-2|x|)
            float th = __fdividef(1.f - t, 1.f + t);      // tanh(|x|)
            th = (x < 0.f) ? -th : th;
            acc += th * wl[e];
        }
        __syncthreads();
    }

    const int n = n0 + tx;
    const int s = s0 + ty;
    if (n < NKEY) {
        float v = (mask[b * NKEY + n] == 0) ? -1e9f : acc;
        scores[(size_t)(b * SEQ + s) * NKEY + n] = v;
    }
}

// ---------------------------------------------------------------------------
// In-place row softmax over N=196. One wave (64 lanes) per row, 4 elems/lane.
// ---------------------------------------------------------------------------
__global__ __launch_bounds__(64) void softmax_kernel(float* __restrict__ sw)
{
    const int row = blockIdx.x;        // b*SEQ + s
    const int lane = threadIdx.x;
    float v[4];
    float mx = -INFINITY;
    #pragma unroll
    for (int k = 0; k < 4; ++k) {
        int n = lane + 64 * k;
        v[k] = (n < NKEY) ? sw[(size_t)row * NKEY + n] : -INFINITY;
        mx = fmaxf(mx, v[k]);
    }
    #pragma unroll
    for (int off = 32; off; off >>= 1) mx = fmaxf(mx, __shfl_xor(mx, off));
    float sum = 0.f;
    #pragma unroll
    for (int k = 0; k < 4; ++k) {
        v[k] = __expf(v[k] - mx);
        if (lane + 64 * k < NKEY) sum += v[k];
    }
    #pragma unroll
    for (int off = 32; off; off >>= 1) sum += __shfl_xor(sum, off);
    const float inv = __fdividef(1.f, sum);
    #pragma unroll
    for (int k = 0; k < 4; ++k) {
        int n = lane + 64 * k;
        if (n < NKEY) sw[(size_t)row * NKEY + n] = v[k] * inv;
    }
}

// ---------------------------------------------------------------------------
// attn[b,s,f] = sum_n weights[b,s,n] * feats[b,n,f]
// Block: 256 consecutive f-columns x 8 s-rows; weights tile in LDS.
// ---------------------------------------------------------------------------
__global__ __launch_bounds__(256) void attn_kernel(
    const float* __restrict__ weights, const float* __restrict__ feats,
    float* __restrict__ out)
{
    const int col = blockIdx.x * 256 + threadIdx.x;
    const int s0  = blockIdx.y * 8;
    const int b   = blockIdx.z;

    __shared__ float wl[8][NKEY];
    for (int i = threadIdx.x; i < 8 * NKEY; i += 256) {
        int s = i / NKEY, n = i % NKEY;
        wl[s][n] = weights[(size_t)(b * SEQ + s0 + s) * NKEY + n];
    }
    __syncthreads();

    float acc[8] = {};
    for (int n = 0; n < NKEY; ++n) {
        float f = feats[(size_t)(b * NKEY + n) * ATT_FEAT + col];
        #pragma unroll
        for (int s = 0; s < 8; ++s) acc[s] += wl[s][n] * f;
    }
    #pragma unroll
    for (int s = 0; s < 8; ++s)
        out[(size_t)(b * SEQ + s0 + s) * ATT_FEAT + col] = acc[s];
}

// ---------------------------------------------------------------------------
extern "C" void kernel_launch(void* const* d_in, const int* in_sizes, int n_in,
                              void* d_out, int out_size, void* d_ws, size_t ws_size,
                              hipStream_t stream)
{
    const float* hidden = (const float*)d_in[0];  // [B,S,H]
    const float* feats  = (const float*)d_in[1];  // [B,N,F]
    const int*   mask   = (const int*)  d_in[2];  // [B,N]
    const float* w_h    = (const float*)d_in[3];  // [H,E]
    const float* w_u    = (const float*)d_in[4];  // [F,E]
    const float* bvec   = (const float*)d_in[5];  // [E]
    const float* wvec   = (const float*)d_in[6];  // [E]

    float* out         = (float*)d_out;
    float* attn_out    = out;                                      // B*S*F
    float* weights_out = out + (size_t)BATCH * SEQ * ATT_FEAT;     // B*S*N

    float* Wh = (float*)d_ws;                          // B*S*E
    float* Uv = Wh + (size_t)BATCH * SEQ * EMBED;      // B*N*E

    // K1: Wh = hidden @ w_h   [1024,1024]x[1024,512]  grid 8x16
    gemm_mfma_split<<<dim3(EMBED / 64, (BATCH * SEQ) / 64), 256, 0, stream>>>(
        hidden, w_h, nullptr, Wh, BATCH * SEQ, EMBED, HIDDEN);

    // K2: Uv = feats @ w_u + b  [3136,2048]x[2048,512]  grid 8x49
    gemm_mfma_split<<<dim3(EMBED / 64, (BATCH * NKEY) / 64), 256, 0, stream>>>(
        feats, w_u, bvec, Uv, BATCH * NKEY, EMBED, ATT_FEAT);

    // K3: scores (+mask) -> weights region of d_out
    scores_kernel<<<dim3((NKEY + 15) / 16, SEQ / 16, BATCH), 256, 0, stream>>>(
        Wh, Uv, wvec, mask, weights_out);

    // K4: softmax in place
    softmax_kernel<<<dim3(BATCH * SEQ), 64, 0, stream>>>(weights_out);

    // K5: attn_feats = weights @ feats
    attn_kernel<<<dim3(ATT_FEAT / 256, SEQ / 8, BATCH), 256, 0, stream>>>(
        weights_out, feats, attn_out);
}

// Round 3
// 187.277 us; speedup vs baseline: 3.4381x; 1.3481x over previous
//
#include <hip/hip_runtime.h>
#include <math.h>

#define BATCH 16
#define SEQ 64
#define NKEY 196
#define HIDDEN 1024
#define ATT_FEAT 2048
#define EMBED 512

using short8  = __attribute__((ext_vector_type(8))) short;
using f32x4   = __attribute__((ext_vector_type(4))) float;
using float4v = __attribute__((ext_vector_type(4))) float;
using uint4v  = __attribute__((ext_vector_type(4))) unsigned;

// exact truncation split: x = hi + lo + O(2^-16 |x|); bit-ops only, no rounding math
__device__ inline void split8(const float* f, short8& hi, short8& lo) {
    uint4v hp, lp;
    #pragma unroll
    for (int p = 0; p < 4; ++p) {
        unsigned u0 = __builtin_bit_cast(unsigned, f[2 * p + 0]);
        unsigned u1 = __builtin_bit_cast(unsigned, f[2 * p + 1]);
        unsigned m0 = u0 & 0xFFFF0000u;
        unsigned m1 = u1 & 0xFFFF0000u;
        hp[p] = m1 | (u0 >> 16);
        float l0 = f[2 * p + 0] - __builtin_bit_cast(float, m0);   // exact (Sterbenz)
        float l1 = f[2 * p + 1] - __builtin_bit_cast(float, m1);
        unsigned v0 = __builtin_bit_cast(unsigned, l0);
        unsigned v1 = __builtin_bit_cast(unsigned, l1);
        lp[p] = (v1 & 0xFFFF0000u) | (v0 >> 16);
    }
    hi = __builtin_bit_cast(short8, hp);
    lo = __builtin_bit_cast(short8, lp);
}

// swizzled byte offset within a [row][128B] LDS tile (T2 pattern)
__device__ inline int swz(int row, int kbyte) {
    return row * 128 + (kbyte ^ ((row & 7) << 4));
}

// ---------------------------------------------------------------------------
// Split-bf16 MFMA GEMM: C[M,N] = A[M,K] @ B[K,N] (+ bias), f32 in/out.
// Tile 64x64, BK=64. 4 waves, each a 32x32 quadrant (2x2 of 16x16x32 frags).
// 3 MFMA products: hi*hi + hi*lo + lo*hi.
// ---------------------------------------------------------------------------
__global__ __launch_bounds__(256) void gemm_mfma_split(
    const float* __restrict__ A, const float* __restrict__ Bm,
    const float* __restrict__ bias, float* __restrict__ C,
    int M, int N, int K)
{
    __shared__ __align__(16) unsigned short AsHi[64 * 64];
    __shared__ __align__(16) unsigned short AsLo[64 * 64];
    __shared__ __align__(16) unsigned short BsHi[64 * 64];
    __shared__ __align__(16) unsigned short BsLo[64 * 64];

    const int tid  = threadIdx.x;
    const int row0 = blockIdx.y * 64;
    const int col0 = blockIdx.x * 64;

    const int lane = tid & 63;
    const int w    = tid >> 6;
    const int wr   = w >> 1;
    const int wc   = w & 1;
    const int l15  = lane & 15;
    const int lg   = lane >> 4;

    const int ar = tid >> 2;
    const int ac = (tid & 3) << 4;
    const int bn = tid & 63;
    const int bk = (tid >> 6) << 4;

    f32x4 acc[2][2] = {};

    char* AsHiB = (char*)AsHi;
    char* AsLoB = (char*)AsLo;
    char* BsHiB = (char*)BsHi;
    char* BsLoB = (char*)BsLo;

    for (int k0 = 0; k0 < K; k0 += 64) {
        {
            const float* Ap = A + (size_t)(row0 + ar) * K + k0 + ac;
            float f[16];
            #pragma unroll
            for (int q = 0; q < 4; ++q) {
                float4v v = *(const float4v*)(Ap + q * 4);
                f[q * 4 + 0] = v.x; f[q * 4 + 1] = v.y;
                f[q * 4 + 2] = v.z; f[q * 4 + 3] = v.w;
            }
            short8 hi0, hi1, lo0, lo1;
            split8(f, hi0, lo0);
            split8(f + 8, hi1, lo1);
            *(short8*)(AsHiB + swz(ar, ac * 2 + 0))  = hi0;
            *(short8*)(AsHiB + swz(ar, ac * 2 + 16)) = hi1;
            *(short8*)(AsLoB + swz(ar, ac * 2 + 0))  = lo0;
            *(short8*)(AsLoB + swz(ar, ac * 2 + 16)) = lo1;
        }
        {
            float f[16];
            #pragma unroll
            for (int j = 0; j < 16; ++j)
                f[j] = Bm[(size_t)(k0 + bk + j) * N + col0 + bn];
            short8 hi0, hi1, lo0, lo1;
            split8(f, hi0, lo0);
            split8(f + 8, hi1, lo1);
            *(short8*)(BsHiB + swz(bn, bk * 2 + 0))  = hi0;
            *(short8*)(BsHiB + swz(bn, bk * 2 + 16)) = hi1;
            *(short8*)(BsLoB + swz(bn, bk * 2 + 0))  = lo0;
            *(short8*)(BsLoB + swz(bn, bk * 2 + 16)) = lo1;
        }
        __syncthreads();

        #pragma unroll
        for (int ksub = 0; ksub < 2; ++ksub) {
            const int kb = ksub * 64 + lg * 16;
            short8 ah[2], al[2], bh[2], bl[2];
            #pragma unroll
            for (int m = 0; m < 2; ++m) {
                int off = swz(wr * 32 + m * 16 + l15, kb);
                ah[m] = *(const short8*)(AsHiB + off);
                al[m] = *(const short8*)(AsLoB + off);
            }
            #pragma unroll
            for (int n = 0; n < 2; ++n) {
                int off = swz(wc * 32 + n * 16 + l15, kb);
                bh[n] = *(const short8*)(BsHiB + off);
                bl[n] = *(const short8*)(BsLoB + off);
            }
            #pragma unroll
            for (int m = 0; m < 2; ++m)
                #pragma unroll
                for (int n = 0; n < 2; ++n) {
                    acc[m][n] = __builtin_amdgcn_mfma_f32_16x16x32_bf16(ah[m], bh[n], acc[m][n], 0, 0, 0);
                    acc[m][n] = __builtin_amdgcn_mfma_f32_16x16x32_bf16(ah[m], bl[n], acc[m][n], 0, 0, 0);
                    acc[m][n] = __builtin_amdgcn_mfma_f32_16x16x32_bf16(al[m], bh[n], acc[m][n], 0, 0, 0);
                }
        }
        __syncthreads();
    }

    #pragma unroll
    for (int m = 0; m < 2; ++m)
        #pragma unroll
        for (int n = 0; n < 2; ++n)
            #pragma unroll
            for (int v = 0; v < 4; ++v) {
                int r = row0 + wr * 32 + m * 16 + lg * 4 + v;
                int c = col0 + wc * 32 + n * 16 + l15;
                float val = acc[m][n][v];
                if (bias) val += bias[c];
                C[(size_t)r * N + c] = val;
            }
}

// ---------------------------------------------------------------------------
// scores[b,s,n] = 2 * sum_e w[e] * sigmoid(2*(Wh+Uv))   (== sum w*tanh + const;
// the constant Sum(w) is softmax-shift-invariant, so it is dropped).
// Block: 16 s x 16 n, e chunked by 64 in LDS, float4 + XOR-swizzle.
// ---------------------------------------------------------------------------
__global__ __launch_bounds__(256) void scores_kernel(
    const float* __restrict__ Wh, const float* __restrict__ Uv,
    const float* __restrict__ wvec, const int* __restrict__ mask,
    float* __restrict__ scores)
{
    const int n0 = blockIdx.x * 16;   // 13 tiles
    const int s0 = blockIdx.y * 16;   // 4 tiles
    const int b  = blockIdx.z;
    const int tid = threadIdx.x;
    const int tx = tid & 15;          // n within tile
    const int ty = tid >> 4;          // s within tile

    __shared__ float whs[16][64];
    __shared__ float uvs[16][64];

    const float KC = -2.8853900817779268f;   // -2*log2(e)

    // staging coords: row r, float4-chunk c4
    const int r  = tid >> 4;
    const int c4 = tid & 15;
    const int sr = s0 + r;
    const int nr_raw = n0 + r;
    const int nr = nr_raw < NKEY ? nr_raw : NKEY - 1;

    const float* WhRow = Wh + (size_t)(b * SEQ + sr) * EMBED;
    const float* UvRow = Uv + (size_t)(b * NKEY + nr) * EMBED;

    float acc0 = 0.f, acc1 = 0.f, acc2 = 0.f, acc3 = 0.f;

    for (int e0 = 0; e0 < EMBED; e0 += 64) {
        float4v wv = *(const float4v*)(WhRow + e0 + c4 * 4);
        float4v uv = *(const float4v*)(UvRow + e0 + c4 * 4);
        *(float4v*)&whs[r][(c4 ^ r) << 2] = wv;
        *(float4v*)&uvs[r][(c4 ^ r) << 2] = uv;
        __syncthreads();

        #pragma unroll
        for (int c = 0; c < 16; ++c) {
            float4v whv = *(const float4v*)&whs[ty][(c ^ ty) << 2];
            float4v uvv = *(const float4v*)&uvs[tx][(c ^ tx) << 2];
            const float w0 = wvec[e0 + c * 4 + 0];   // uniform -> scalar load
            const float w1 = wvec[e0 + c * 4 + 1];
            const float w2 = wvec[e0 + c * 4 + 2];
            const float w3 = wvec[e0 + c * 4 + 3];
            float t0 = __builtin_amdgcn_exp2f(KC * (whv.x + uvv.x));
            float t1 = __builtin_amdgcn_exp2f(KC * (whv.y + uvv.y));
            float t2 = __builtin_amdgcn_exp2f(KC * (whv.z + uvv.z));
            float t3 = __builtin_amdgcn_exp2f(KC * (whv.w + uvv.w));
            acc0 = fmaf(w0, __builtin_amdgcn_rcpf(1.f + t0), acc0);
            acc1 = fmaf(w1, __builtin_amdgcn_rcpf(1.f + t1), acc1);
            acc2 = fmaf(w2, __builtin_amdgcn_rcpf(1.f + t2), acc2);
            acc3 = fmaf(w3, __builtin_amdgcn_rcpf(1.f + t3), acc3);
        }
        __syncthreads();
    }

    float sc = 2.f * ((acc0 + acc1) + (acc2 + acc3));
    const int n = n0 + tx;
    if (n < NKEY) {
        float v = (mask[b * NKEY + n] == 0) ? -1e9f : sc;
        scores[(size_t)(b * SEQ + s0 + ty) * NKEY + n] = v;
    }
}

// ---------------------------------------------------------------------------
// In-place row softmax over N=196. One wave per row.
// ---------------------------------------------------------------------------
__global__ __launch_bounds__(64) void softmax_kernel(float* __restrict__ sw)
{
    const int row = blockIdx.x;
    const int lane = threadIdx.x;
    float v[4];
    float mx = -INFINITY;
    #pragma unroll
    for (int k = 0; k < 4; ++k) {
        int n = lane + 64 * k;
        v[k] = (n < NKEY) ? sw[(size_t)row * NKEY + n] : -INFINITY;
        mx = fmaxf(mx, v[k]);
    }
    #pragma unroll
    for (int off = 32; off; off >>= 1) mx = fmaxf(mx, __shfl_xor(mx, off));
    float sum = 0.f;
    #pragma unroll
    for (int k = 0; k < 4; ++k) {
        v[k] = __expf(v[k] - mx);
        if (lane + 64 * k < NKEY) sum += v[k];
    }
    #pragma unroll
    for (int off = 32; off; off >>= 1) sum += __shfl_xor(sum, off);
    const float inv = __fdividef(1.f, sum);
    #pragma unroll
    for (int k = 0; k < 4; ++k) {
        int n = lane + 64 * k;
        if (n < NKEY) sw[(size_t)row * NKEY + n] = v[k] * inv;
    }
}

// ---------------------------------------------------------------------------
// attn[b,s,f] = sum_n weights[b,s,n] * feats[b,n,f]
// ---------------------------------------------------------------------------
__global__ __launch_bounds__(256) void attn_kernel(
    const float* __restrict__ weights, const float* __restrict__ feats,
    float* __restrict__ out)
{
    const int col = blockIdx.x * 256 + threadIdx.x;
    const int s0  = blockIdx.y * 8;
    const int b   = blockIdx.z;

    __shared__ float wl[8][NKEY];
    for (int i = threadIdx.x; i < 8 * NKEY; i += 256) {
        int s = i / NKEY, n = i % NKEY;
        wl[s][n] = weights[(size_t)(b * SEQ + s0 + s) * NKEY + n];
    }
    __syncthreads();

    float acc[8] = {};
    for (int n = 0; n < NKEY; ++n) {
        float f = feats[(size_t)(b * NKEY + n) * ATT_FEAT + col];
        #pragma unroll
        for (int s = 0; s < 8; ++s) acc[s] += wl[s][n] * f;
    }
    #pragma unroll
    for (int s = 0; s < 8; ++s)
        out[(size_t)(b * SEQ + s0 + s) * ATT_FEAT + col] = acc[s];
}

// ---------------------------------------------------------------------------
extern "C" void kernel_launch(void* const* d_in, const int* in_sizes, int n_in,
                              void* d_out, int out_size, void* d_ws, size_t ws_size,
                              hipStream_t stream)
{
    const float* hidden = (const float*)d_in[0];
    const float* feats  = (const float*)d_in[1];
    const int*   mask   = (const int*)  d_in[2];
    const float* w_h    = (const float*)d_in[3];
    const float* w_u    = (const float*)d_in[4];
    const float* bvec   = (const float*)d_in[5];
    const float* wvec   = (const float*)d_in[6];

    float* out         = (float*)d_out;
    float* attn_out    = out;
    float* weights_out = out + (size_t)BATCH * SEQ * ATT_FEAT;

    float* Wh = (float*)d_ws;
    float* Uv = Wh + (size_t)BATCH * SEQ * EMBED;

    gemm_mfma_split<<<dim3(EMBED / 64, (BATCH * SEQ) / 64), 256, 0, stream>>>(
        hidden, w_h, nullptr, Wh, BATCH * SEQ, EMBED, HIDDEN);

    gemm_mfma_split<<<dim3(EMBED / 64, (BATCH * NKEY) / 64), 256, 0, stream>>>(
        feats, w_u, bvec, Uv, BATCH * NKEY, EMBED, ATT_FEAT);

    scores_kernel<<<dim3((NKEY + 15) / 16, SEQ / 16, BATCH), 256, 0, stream>>>(
        Wh, Uv, wvec, mask, weights_out);

    softmax_kernel<<<dim3(BATCH * SEQ), 64, 0, stream>>>(weights_out);

    attn_kernel<<<dim3(ATT_FEAT / 256, SEQ / 8, BATCH), 256, 0, stream>>>(
        weights_out, feats, attn_out);
}

// Round 4
// 149.697 us; speedup vs baseline: 4.3012x; 1.2510x over previous
//
#include <hip/hip_runtime.h>
#include <math.h>

#define BATCH 16
#define SEQ 64
#define NKEY 196
#define HIDDEN 1024
#define ATT_FEAT 2048
#define EMBED 512

using short8  = __attribute__((ext_vector_type(8))) short;
using f32x4   = __attribute__((ext_vector_type(4))) float;
using float4v = __attribute__((ext_vector_type(4))) float;
using uint4v  = __attribute__((ext_vector_type(4))) unsigned;

// exact truncation split: x = hi + lo + O(2^-16 |x|); bit-ops only
__device__ inline void split8(const float* f, short8& hi, short8& lo) {
    uint4v hp, lp;
    #pragma unroll
    for (int p = 0; p < 4; ++p) {
        unsigned u0 = __builtin_bit_cast(unsigned, f[2 * p + 0]);
        unsigned u1 = __builtin_bit_cast(unsigned, f[2 * p + 1]);
        unsigned m0 = u0 & 0xFFFF0000u;
        unsigned m1 = u1 & 0xFFFF0000u;
        hp[p] = m1 | (u0 >> 16);
        float l0 = f[2 * p + 0] - __builtin_bit_cast(float, m0);
        float l1 = f[2 * p + 1] - __builtin_bit_cast(float, m1);
        unsigned v0 = __builtin_bit_cast(unsigned, l0);
        unsigned v1 = __builtin_bit_cast(unsigned, l1);
        lp[p] = (v1 & 0xFFFF0000u) | (v0 >> 16);
    }
    hi = __builtin_bit_cast(short8, hp);
    lo = __builtin_bit_cast(short8, lp);
}

// swizzled byte offset within a [row][128B] LDS tile (T2 pattern)
__device__ inline int swz(int row, int kbyte) {
    return row * 128 + (kbyte ^ ((row & 7) << 4));
}

// ---------------------------------------------------------------------------
// Split-bf16 MFMA GEMM: C[M,N] = A[M,K] @ B[K,N] (+ bias), f32 in/out.
// Tile 64x64, BK=64. 4 waves, each a 32x32 quadrant (2x2 of 16x16x32 frags).
// 3 MFMA products: hi*hi + hi*lo + lo*hi.
// ---------------------------------------------------------------------------
__global__ __launch_bounds__(256) void gemm_mfma_split(
    const float* __restrict__ A, const float* __restrict__ Bm,
    const float* __restrict__ bias, float* __restrict__ C,
    int M, int N, int K)
{
    __shared__ __align__(16) unsigned short AsHi[64 * 64];
    __shared__ __align__(16) unsigned short AsLo[64 * 64];
    __shared__ __align__(16) unsigned short BsHi[64 * 64];
    __shared__ __align__(16) unsigned short BsLo[64 * 64];

    const int tid  = threadIdx.x;
    const int row0 = blockIdx.y * 64;
    const int col0 = blockIdx.x * 64;

    const int lane = tid & 63;
    const int w    = tid >> 6;
    const int wr   = w >> 1;
    const int wc   = w & 1;
    const int l15  = lane & 15;
    const int lg   = lane >> 4;

    const int ar = tid >> 2;
    const int ac = (tid & 3) << 4;
    const int bn = tid & 63;
    const int bk = (tid >> 6) << 4;

    f32x4 acc[2][2] = {};

    char* AsHiB = (char*)AsHi;
    char* AsLoB = (char*)AsLo;
    char* BsHiB = (char*)BsHi;
    char* BsLoB = (char*)BsLo;

    for (int k0 = 0; k0 < K; k0 += 64) {
        {
            const float* Ap = A + (size_t)(row0 + ar) * K + k0 + ac;
            float f[16];
            #pragma unroll
            for (int q = 0; q < 4; ++q) {
                float4v v = *(const float4v*)(Ap + q * 4);
                f[q * 4 + 0] = v.x; f[q * 4 + 1] = v.y;
                f[q * 4 + 2] = v.z; f[q * 4 + 3] = v.w;
            }
            short8 hi0, hi1, lo0, lo1;
            split8(f, hi0, lo0);
            split8(f + 8, hi1, lo1);
            *(short8*)(AsHiB + swz(ar, ac * 2 + 0))  = hi0;
            *(short8*)(AsHiB + swz(ar, ac * 2 + 16)) = hi1;
            *(short8*)(AsLoB + swz(ar, ac * 2 + 0))  = lo0;
            *(short8*)(AsLoB + swz(ar, ac * 2 + 16)) = lo1;
        }
        {
            float f[16];
            #pragma unroll
            for (int j = 0; j < 16; ++j)
                f[j] = Bm[(size_t)(k0 + bk + j) * N + col0 + bn];
            short8 hi0, hi1, lo0, lo1;
            split8(f, hi0, lo0);
            split8(f + 8, hi1, lo1);
            *(short8*)(BsHiB + swz(bn, bk * 2 + 0))  = hi0;
            *(short8*)(BsHiB + swz(bn, bk * 2 + 16)) = hi1;
            *(short8*)(BsLoB + swz(bn, bk * 2 + 0))  = lo0;
            *(short8*)(BsLoB + swz(bn, bk * 2 + 16)) = lo1;
        }
        __syncthreads();

        #pragma unroll
        for (int ksub = 0; ksub < 2; ++ksub) {
            const int kb = ksub * 64 + lg * 16;
            short8 ah[2], al[2], bh[2], bl[2];
            #pragma unroll
            for (int m = 0; m < 2; ++m) {
                int off = swz(wr * 32 + m * 16 + l15, kb);
                ah[m] = *(const short8*)(AsHiB + off);
                al[m] = *(const short8*)(AsLoB + off);
            }
            #pragma unroll
            for (int n = 0; n < 2; ++n) {
                int off = swz(wc * 32 + n * 16 + l15, kb);
                bh[n] = *(const short8*)(BsHiB + off);
                bl[n] = *(const short8*)(BsLoB + off);
            }
            #pragma unroll
            for (int m = 0; m < 2; ++m)
                #pragma unroll
                for (int n = 0; n < 2; ++n) {
                    acc[m][n] = __builtin_amdgcn_mfma_f32_16x16x32_bf16(ah[m], bh[n], acc[m][n], 0, 0, 0);
                    acc[m][n] = __builtin_amdgcn_mfma_f32_16x16x32_bf16(ah[m], bl[n], acc[m][n], 0, 0, 0);
                    acc[m][n] = __builtin_amdgcn_mfma_f32_16x16x32_bf16(al[m], bh[n], acc[m][n], 0, 0, 0);
                }
        }
        __syncthreads();
    }

    #pragma unroll
    for (int m = 0; m < 2; ++m)
        #pragma unroll
        for (int n = 0; n < 2; ++n)
            #pragma unroll
            for (int v = 0; v < 4; ++v) {
                int r = row0 + wr * 32 + m * 16 + lg * 4 + v;
                int c = col0 + wc * 32 + n * 16 + l15;
                float val = acc[m][n][v];
                if (bias) val += bias[c];
                C[(size_t)r * N + c] = val;
            }
}

// ---------------------------------------------------------------------------
// scores[b,s,n] = 2 * sum_e w[e] * sigmoid(2*(Wh+Uv))  (Sum(w) shift dropped)
// ---------------------------------------------------------------------------
__global__ __launch_bounds__(256) void scores_kernel(
    const float* __restrict__ Wh, const float* __restrict__ Uv,
    const float* __restrict__ wvec, const int* __restrict__ mask,
    float* __restrict__ scores)
{
    const int n0 = blockIdx.x * 16;
    const int s0 = blockIdx.y * 16;
    const int b  = blockIdx.z;
    const int tid = threadIdx.x;
    const int tx = tid & 15;
    const int ty = tid >> 4;

    __shared__ float whs[16][64];
    __shared__ float uvs[16][64];

    const float KC = -2.8853900817779268f;   // -2*log2(e)

    const int r  = tid >> 4;
    const int c4 = tid & 15;
    const int sr = s0 + r;
    const int nr_raw = n0 + r;
    const int nr = nr_raw < NKEY ? nr_raw : NKEY - 1;

    const float* WhRow = Wh + (size_t)(b * SEQ + sr) * EMBED;
    const float* UvRow = Uv + (size_t)(b * NKEY + nr) * EMBED;

    float acc0 = 0.f, acc1 = 0.f, acc2 = 0.f, acc3 = 0.f;

    for (int e0 = 0; e0 < EMBED; e0 += 64) {
        float4v wv = *(const float4v*)(WhRow + e0 + c4 * 4);
        float4v uv = *(const float4v*)(UvRow + e0 + c4 * 4);
        *(float4v*)&whs[r][(c4 ^ r) << 2] = wv;
        *(float4v*)&uvs[r][(c4 ^ r) << 2] = uv;
        __syncthreads();

        #pragma unroll
        for (int c = 0; c < 16; ++c) {
            float4v whv = *(const float4v*)&whs[ty][(c ^ ty) << 2];
            float4v uvv = *(const float4v*)&uvs[tx][(c ^ tx) << 2];
            const float w0 = wvec[e0 + c * 4 + 0];
            const float w1 = wvec[e0 + c * 4 + 1];
            const float w2 = wvec[e0 + c * 4 + 2];
            const float w3 = wvec[e0 + c * 4 + 3];
            float t0 = __builtin_amdgcn_exp2f(KC * (whv.x + uvv.x));
            float t1 = __builtin_amdgcn_exp2f(KC * (whv.y + uvv.y));
            float t2 = __builtin_amdgcn_exp2f(KC * (whv.z + uvv.z));
            float t3 = __builtin_amdgcn_exp2f(KC * (whv.w + uvv.w));
            acc0 = fmaf(w0, __builtin_amdgcn_rcpf(1.f + t0), acc0);
            acc1 = fmaf(w1, __builtin_amdgcn_rcpf(1.f + t1), acc1);
            acc2 = fmaf(w2, __builtin_amdgcn_rcpf(1.f + t2), acc2);
            acc3 = fmaf(w3, __builtin_amdgcn_rcpf(1.f + t3), acc3);
        }
        __syncthreads();
    }

    float sc = 2.f * ((acc0 + acc1) + (acc2 + acc3));
    const int n = n0 + tx;
    if (n < NKEY) {
        float v = (mask[b * NKEY + n] == 0) ? -1e9f : sc;
        scores[(size_t)(b * SEQ + s0 + ty) * NKEY + n] = v;
    }
}

// ---------------------------------------------------------------------------
// In-place row softmax over N=196. One wave per row.
// ---------------------------------------------------------------------------
__global__ __launch_bounds__(64) void softmax_kernel(float* __restrict__ sw)
{
    const int row = blockIdx.x;
    const int lane = threadIdx.x;
    float v[4];
    float mx = -INFINITY;
    #pragma unroll
    for (int k = 0; k < 4; ++k) {
        int n = lane + 64 * k;
        v[k] = (n < NKEY) ? sw[(size_t)row * NKEY + n] : -INFINITY;
        mx = fmaxf(mx, v[k]);
    }
    #pragma unroll
    for (int off = 32; off; off >>= 1) mx = fmaxf(mx, __shfl_xor(mx, off));
    float sum = 0.f;
    #pragma unroll
    for (int k = 0; k < 4; ++k) {
        v[k] = __expf(v[k] - mx);
        if (lane + 64 * k < NKEY) sum += v[k];
    }
    #pragma unroll
    for (int off = 32; off; off >>= 1) sum += __shfl_xor(sum, off);
    const float inv = __fdividef(1.f, sum);
    #pragma unroll
    for (int k = 0; k < 4; ++k) {
        int n = lane + 64 * k;
        if (n < NKEY) sw[(size_t)row * NKEY + n] = v[k] * inv;
    }
}

// ---------------------------------------------------------------------------
// attn[b,s,f] = sum_n weights[b,s,n] * feats[b,n,f]
// Block: 256 threads x float4 = 1024 f-cols, 8 s-rows. Grid (2, 8, 16).
// Weights staged TRANSPOSED wt[n][s]: per n-iter = 2 broadcast ds_read_b128
// + 32 packed FMAs; feats via 16B/lane coalesced float4 loads.
// ---------------------------------------------------------------------------
__global__ __launch_bounds__(256) void attn_kernel(
    const float* __restrict__ weights, const float* __restrict__ feats,
    float* __restrict__ out)
{
    const int t   = threadIdx.x;
    const int col = blockIdx.x * 1024 + t * 4;
    const int s0  = blockIdx.y * 8;
    const int b   = blockIdx.z;

    __shared__ float wt[NKEY][8];   // transposed: wt[n][s]
    for (int i = t; i < 8 * NKEY; i += 256) {
        int s = i / NKEY, n = i % NKEY;   // coalesced read
        wt[n][s] = weights[(size_t)(b * SEQ + s0 + s) * NKEY + n];
    }
    __syncthreads();

    const float* fp = feats + (size_t)b * NKEY * ATT_FEAT + col;

    float4v acc[8] = {};
    #pragma unroll 4
    for (int n = 0; n < NKEY; ++n) {
        float4v f  = *(const float4v*)(fp + (size_t)n * ATT_FEAT);
        float4v w0 = *(const float4v*)&wt[n][0];   // broadcast
        float4v w1 = *(const float4v*)&wt[n][4];   // broadcast
        acc[0] += w0.x * f;
        acc[1] += w0.y * f;
        acc[2] += w0.z * f;
        acc[3] += w0.w * f;
        acc[4] += w1.x * f;
        acc[5] += w1.y * f;
        acc[6] += w1.z * f;
        acc[7] += w1.w * f;
    }

    float* op = out + (size_t)(b * SEQ + s0) * ATT_FEAT + col;
    #pragma unroll
    for (int s = 0; s < 8; ++s)
        *(float4v*)(op + (size_t)s * ATT_FEAT) = acc[s];
}

// ---------------------------------------------------------------------------
extern "C" void kernel_launch(void* const* d_in, const int* in_sizes, int n_in,
                              void* d_out, int out_size, void* d_ws, size_t ws_size,
                              hipStream_t stream)
{
    const float* hidden = (const float*)d_in[0];
    const float* feats  = (const float*)d_in[1];
    const int*   mask   = (const int*)  d_in[2];
    const float* w_h    = (const float*)d_in[3];
    const float* w_u    = (const float*)d_in[4];
    const float* bvec   = (const float*)d_in[5];
    const float* wvec   = (const float*)d_in[6];

    float* out         = (float*)d_out;
    float* attn_out    = out;
    float* weights_out = out + (size_t)BATCH * SEQ * ATT_FEAT;

    float* Wh = (float*)d_ws;
    float* Uv = Wh + (size_t)BATCH * SEQ * EMBED;

    gemm_mfma_split<<<dim3(EMBED / 64, (BATCH * SEQ) / 64), 256, 0, stream>>>(
        hidden, w_h, nullptr, Wh, BATCH * SEQ, EMBED, HIDDEN);

    gemm_mfma_split<<<dim3(EMBED / 64, (BATCH * NKEY) / 64), 256, 0, stream>>>(
        feats, w_u, bvec, Uv, BATCH * NKEY, EMBED, ATT_FEAT);

    scores_kernel<<<dim3((NKEY + 15) / 16, SEQ / 16, BATCH), 256, 0, stream>>>(
        Wh, Uv, wvec, mask, weights_out);

    softmax_kernel<<<dim3(BATCH * SEQ), 64, 0, stream>>>(weights_out);

    attn_kernel<<<dim3(ATT_FEAT / 1024, SEQ / 8, BATCH), 256, 0, stream>>>(
        weights_out, feats, attn_out);
}

// Round 6
// 140.937 us; speedup vs baseline: 4.5686x; 1.0622x over previous
//
#include <hip/hip_runtime.h>
#include <math.h>

#define BATCH 16
#define SEQ 64
#define NKEY 196
#define HIDDEN 1024
#define ATT_FEAT 2048
#define EMBED 512

using short8   = __attribute__((ext_vector_type(8))) short;
using f32x4    = __attribute__((ext_vector_type(4))) float;
using float4v  = __attribute__((ext_vector_type(4))) float;
using uint4v   = __attribute__((ext_vector_type(4))) unsigned;
using ushort4v = __attribute__((ext_vector_type(4))) unsigned short;

// exact truncation split: x = hi + lo + O(2^-16 |x|); bit-ops only
__device__ inline void split8(const float* f, short8& hi, short8& lo) {
    uint4v hp, lp;
    #pragma unroll
    for (int p = 0; p < 4; ++p) {
        unsigned u0 = __builtin_bit_cast(unsigned, f[2 * p + 0]);
        unsigned u1 = __builtin_bit_cast(unsigned, f[2 * p + 1]);
        unsigned m0 = u0 & 0xFFFF0000u;
        unsigned m1 = u1 & 0xFFFF0000u;
        hp[p] = m1 | (u0 >> 16);
        float l0 = f[2 * p + 0] - __builtin_bit_cast(float, m0);
        float l1 = f[2 * p + 1] - __builtin_bit_cast(float, m1);
        unsigned v0 = __builtin_bit_cast(unsigned, l0);
        unsigned v1 = __builtin_bit_cast(unsigned, l1);
        lp[p] = (v1 & 0xFFFF0000u) | (v0 >> 16);
    }
    hi = __builtin_bit_cast(short8, hp);
    lo = __builtin_bit_cast(short8, lp);
}

__device__ inline void split1(float x, unsigned short& h, unsigned short& l) {
    unsigned u = __builtin_bit_cast(unsigned, x);
    unsigned m = u & 0xFFFF0000u;
    h = (unsigned short)(u >> 16);
    float lo = x - __builtin_bit_cast(float, m);
    l = (unsigned short)(__builtin_bit_cast(unsigned, lo) >> 16);
}

// swizzled byte offset within a [row][128B] LDS tile (T2 pattern)
__device__ inline int swz(int row, int kbyte) {
    return row * 128 + (kbyte ^ ((row & 7) << 4));
}

// ---------------------------------------------------------------------------
// One-shot: W [K][N] f32  ->  Th/Tl [N][K] bf16 (truncation hi/lo split).
// 32x32 LDS tile transpose. Grid (K/32, N/32).
// ---------------------------------------------------------------------------
__global__ __launch_bounds__(256) void prep_split_transpose(
    const float* __restrict__ W, unsigned short* __restrict__ Th,
    unsigned short* __restrict__ Tl, int K, int N)
{
    __shared__ float tile[32][33];
    const int k0 = blockIdx.x * 32, n0 = blockIdx.y * 32;
    const int tid = threadIdx.x;

    {
        const int kl = tid >> 3;            // 0..31
        const int ng = (tid & 7) * 4;       // 0..28
        float4v v = *(const float4v*)(W + (size_t)(k0 + kl) * N + n0 + ng);
        tile[kl][ng + 0] = v.x; tile[kl][ng + 1] = v.y;
        tile[kl][ng + 2] = v.z; tile[kl][ng + 3] = v.w;
    }
    __syncthreads();
    {
        const int nl = tid >> 3;            // 0..31
        const int kg = (tid & 7) * 4;       // 0..28
        ushort4v h, l;
        #pragma unroll
        for (int j = 0; j < 4; ++j) {
            unsigned short hh, ll;
            split1(tile[kg + j][nl], hh, ll);
            h[j] = hh; l[j] = ll;
        }
        size_t off = (size_t)(n0 + nl) * K + k0 + kg;
        *(ushort4v*)(Th + off) = h;
        *(ushort4v*)(Tl + off) = l;
    }
}

// ---------------------------------------------------------------------------
// Split-bf16 MFMA GEMM, weights pre-split/transposed:
//   C[M,N] = A[M,K](f32) @ B[K,N] (+bias), B given as BTh/BTl [N][K] bf16.
// Tile 64x64, BK=64, double-buffered LDS, 2-phase pipeline, XCD swizzle.
// 4 waves, each a 32x32 quadrant; 3 MFMA products hi*hi + hi*lo + lo*hi.
// Requires M%64==0, N%64==0, K%64==0, grid%8==0.
// ---------------------------------------------------------------------------
__global__ __launch_bounds__(256) void gemm_mfma_ws(
    const float* __restrict__ A, const unsigned short* __restrict__ BTh,
    const unsigned short* __restrict__ BTl, const float* __restrict__ bias,
    float* __restrict__ C, int N, int K)
{
    __shared__ __align__(16) unsigned short AsHi[2][64 * 64];
    __shared__ __align__(16) unsigned short AsLo[2][64 * 64];
    __shared__ __align__(16) unsigned short BsHi[2][64 * 64];
    __shared__ __align__(16) unsigned short BsLo[2][64 * 64];

    const int ncol = N >> 6;
    const int G = gridDim.x;
    const int hh = blockIdx.x;
    const int t0 = (hh & 7) * (G >> 3) + (hh >> 3);   // XCD-contiguous tiles
    const int row0 = (t0 / ncol) << 6;
    const int col0 = (t0 % ncol) << 6;

    const int tid  = threadIdx.x;
    const int lane = tid & 63;
    const int w    = tid >> 6;
    const int wr   = w >> 1;
    const int wc   = w & 1;
    const int l15  = lane & 15;
    const int lg   = lane >> 4;

    // staging coords (row=tid>>2, k-chunk=(tid&3)*16)
    const int ar = tid >> 2;
    const int ac = (tid & 3) << 4;

    const float*          Arow = A   + (size_t)(row0 + ar) * K + ac;
    const unsigned short* Bhp  = BTh + (size_t)(col0 + ar) * K + ac;
    const unsigned short* Blp  = BTl + (size_t)(col0 + ar) * K + ac;

    f32x4 acc[2][2] = {};
    float Af[16];
    short8 Rbh0, Rbh1, Rbl0, Rbl1;

    const int sw0 = swz(ar, ac * 2);
    const int sw1 = swz(ar, ac * 2 + 16);

    auto issue_loads = [&](int k0) {
        #pragma unroll
        for (int q = 0; q < 4; ++q) {
            float4v v = *(const float4v*)(Arow + k0 + q * 4);
            Af[q*4+0] = v.x; Af[q*4+1] = v.y;
            Af[q*4+2] = v.z; Af[q*4+3] = v.w;
        }
        Rbh0 = *(const short8*)(Bhp + k0);
        Rbh1 = *(const short8*)(Bhp + k0 + 8);
        Rbl0 = *(const short8*)(Blp + k0);
        Rbl1 = *(const short8*)(Blp + k0 + 8);
    };
    auto write_bufs = [&](int c) {
        short8 hi0, hi1, lo0, lo1;
        split8(Af, hi0, lo0);
        split8(Af + 8, hi1, lo1);
        char* AH = (char*)AsHi[c]; char* AL = (char*)AsLo[c];
        char* BH = (char*)BsHi[c]; char* BL = (char*)BsLo[c];
        *(short8*)(AH + sw0) = hi0;  *(short8*)(AH + sw1) = hi1;
        *(short8*)(AL + sw0) = lo0;  *(short8*)(AL + sw1) = lo1;
        *(short8*)(BH + sw0) = Rbh0; *(short8*)(BH + sw1) = Rbh1;
        *(short8*)(BL + sw0) = Rbl0; *(short8*)(BL + sw1) = Rbl1;
    };

    const int nt = K >> 6;
    issue_loads(0);
    write_bufs(0);

    for (int t = 0; t < nt; ++t) {
        __syncthreads();
        const int cur = t & 1;
        if (t + 1 < nt) issue_loads((t + 1) << 6);

        const char* AH = (const char*)AsHi[cur];
        const char* AL = (const char*)AsLo[cur];
        const char* BH = (const char*)BsHi[cur];
        const char* BL = (const char*)BsLo[cur];
        #pragma unroll
        for (int ksub = 0; ksub < 2; ++ksub) {
            const int kb = ksub * 64 + lg * 16;
            short8 ah[2], al[2], bh[2], bl[2];
            #pragma unroll
            for (int m = 0; m < 2; ++m) {
                int off = swz(wr * 32 + m * 16 + l15, kb);
                ah[m] = *(const short8*)(AH + off);
                al[m] = *(const short8*)(AL + off);
            }
            #pragma unroll
            for (int n = 0; n < 2; ++n) {
                int off = swz(wc * 32 + n * 16 + l15, kb);
                bh[n] = *(const short8*)(BH + off);
                bl[n] = *(const short8*)(BL + off);
            }
            #pragma unroll
            for (int m = 0; m < 2; ++m)
                #pragma unroll
                for (int n = 0; n < 2; ++n) {
                    acc[m][n] = __builtin_amdgcn_mfma_f32_16x16x32_bf16(ah[m], bh[n], acc[m][n], 0, 0, 0);
                    acc[m][n] = __builtin_amdgcn_mfma_f32_16x16x32_bf16(ah[m], bl[n], acc[m][n], 0, 0, 0);
                    acc[m][n] = __builtin_amdgcn_mfma_f32_16x16x32_bf16(al[m], bh[n], acc[m][n], 0, 0, 0);
                }
        }
        if (t + 1 < nt) write_bufs(cur ^ 1);
    }

    #pragma unroll
    for (int m = 0; m < 2; ++m)
        #pragma unroll
        for (int n = 0; n < 2; ++n)
            #pragma unroll
            for (int v = 0; v < 4; ++v) {
                int r = row0 + wr * 32 + m * 16 + lg * 4 + v;
                int c = col0 + wc * 32 + n * 16 + l15;
                float val = acc[m][n][v];
                if (bias) val += bias[c];
                C[(size_t)r * N + c] = val;
            }
}

// ---------------------------------------------------------------------------
// scores[b,s,n] = 2 * sum_e w[e] * sigmoid(2*(Wh+Uv))  (Sum(w) shift dropped)
// ---------------------------------------------------------------------------
__global__ __launch_bounds__(256) void scores_kernel(
    const float* __restrict__ Wh, const float* __restrict__ Uv,
    const float* __restrict__ wvec, const int* __restrict__ mask,
    float* __restrict__ scores)
{
    const int n0 = blockIdx.x * 16;
    const int s0 = blockIdx.y * 16;
    const int b  = blockIdx.z;
    const int tid = threadIdx.x;
    const int tx = tid & 15;
    const int ty = tid >> 4;

    __shared__ float whs[16][64];
    __shared__ float uvs[16][64];

    const float KC = -2.8853900817779268f;   // -2*log2(e)

    const int r  = tid >> 4;
    const int c4 = tid & 15;
    const int sr = s0 + r;
    const int nr_raw = n0 + r;
    const int nr = nr_raw < NKEY ? nr_raw : NKEY - 1;

    const float* WhRow = Wh + (size_t)(b * SEQ + sr) * EMBED;
    const float* UvRow = Uv + (size_t)(b * NKEY + nr) * EMBED;

    float acc0 = 0.f, acc1 = 0.f, acc2 = 0.f, acc3 = 0.f;

    for (int e0 = 0; e0 < EMBED; e0 += 64) {
        float4v wv = *(const float4v*)(WhRow + e0 + c4 * 4);
        float4v uv = *(const float4v*)(UvRow + e0 + c4 * 4);
        *(float4v*)&whs[r][(c4 ^ r) << 2] = wv;
        *(float4v*)&uvs[r][(c4 ^ r) << 2] = uv;
        __syncthreads();

        #pragma unroll
        for (int c = 0; c < 16; ++c) {
            float4v whv = *(const float4v*)&whs[ty][(c ^ ty) << 2];
            float4v uvv = *(const float4v*)&uvs[tx][(c ^ tx) << 2];
            const float w0 = wvec[e0 + c * 4 + 0];
            const float w1 = wvec[e0 + c * 4 + 1];
            const float w2 = wvec[e0 + c * 4 + 2];
            const float w3 = wvec[e0 + c * 4 + 3];
            float t0 = __builtin_amdgcn_exp2f(KC * (whv.x + uvv.x));
            float t1 = __builtin_amdgcn_exp2f(KC * (whv.y + uvv.y));
            float t2 = __builtin_amdgcn_exp2f(KC * (whv.z + uvv.z));
            float t3 = __builtin_amdgcn_exp2f(KC * (whv.w + uvv.w));
            acc0 = fmaf(w0, __builtin_amdgcn_rcpf(1.f + t0), acc0);
            acc1 = fmaf(w1, __builtin_amdgcn_rcpf(1.f + t1), acc1);
            acc2 = fmaf(w2, __builtin_amdgcn_rcpf(1.f + t2), acc2);
            acc3 = fmaf(w3, __builtin_amdgcn_rcpf(1.f + t3), acc3);
        }
        __syncthreads();
    }

    float sc = 2.f * ((acc0 + acc1) + (acc2 + acc3));
    const int n = n0 + tx;
    if (n < NKEY) {
        float v = (mask[b * NKEY + n] == 0) ? -1e9f : sc;
        scores[(size_t)(b * SEQ + s0 + ty) * NKEY + n] = v;
    }
}

// ---------------------------------------------------------------------------
// In-place row softmax over N=196. One wave per row.
// ---------------------------------------------------------------------------
__global__ __launch_bounds__(64) void softmax_kernel(float* __restrict__ sw)
{
    const int row = blockIdx.x;
    const int lane = threadIdx.x;
    float v[4];
    float mx = -INFINITY;
    #pragma unroll
    for (int k = 0; k < 4; ++k) {
        int n = lane + 64 * k;
        v[k] = (n < NKEY) ? sw[(size_t)row * NKEY + n] : -INFINITY;
        mx = fmaxf(mx, v[k]);
    }
    #pragma unroll
    for (int off = 32; off; off >>= 1) mx = fmaxf(mx, __shfl_xor(mx, off));
    float sum = 0.f;
    #pragma unroll
    for (int k = 0; k < 4; ++k) {
        v[k] = __expf(v[k] - mx);
        if (lane + 64 * k < NKEY) sum += v[k];
    }
    #pragma unroll
    for (int off = 32; off; off >>= 1) sum += __shfl_xor(sum, off);
    const float inv = __fdividef(1.f, sum);
    #pragma unroll
    for (int k = 0; k < 4; ++k) {
        int n = lane + 64 * k;
        if (n < NKEY) sw[(size_t)row * NKEY + n] = v[k] * inv;
    }
}

// ---------------------------------------------------------------------------
// attn[b,s,f] = sum_n weights[b,s,n] * feats[b,n,f]
// 256 threads x float4 = 1024 f-cols, 8 s-rows; weights transposed in LDS.
// ---------------------------------------------------------------------------
__global__ __launch_bounds__(256) void attn_kernel(
    const float* __restrict__ weights, const float* __restrict__ feats,
    float* __restrict__ out)
{
    const int t   = threadIdx.x;
    const int col = blockIdx.x * 1024 + t * 4;
    const int s0  = blockIdx.y * 8;
    const int b   = blockIdx.z;

    __shared__ float wt[NKEY][8];
    for (int i = t; i < 8 * NKEY; i += 256) {
        int s = i / NKEY, n = i % NKEY;
        wt[n][s] = weights[(size_t)(b * SEQ + s0 + s) * NKEY + n];
    }
    __syncthreads();

    const float* fp = feats + (size_t)b * NKEY * ATT_FEAT + col;

    float4v acc[8] = {};
    #pragma unroll 4
    for (int n = 0; n < NKEY; ++n) {
        float4v f  = *(const float4v*)(fp + (size_t)n * ATT_FEAT);
        float4v w0 = *(const float4v*)&wt[n][0];
        float4v w1 = *(const float4v*)&wt[n][4];
        acc[0] += w0.x * f;
        acc[1] += w0.y * f;
        acc[2] += w0.z * f;
        acc[3] += w0.w * f;
        acc[4] += w1.x * f;
        acc[5] += w1.y * f;
        acc[6] += w1.z * f;
        acc[7] += w1.w * f;
    }

    float* op = out + (size_t)(b * SEQ + s0) * ATT_FEAT + col;
    #pragma unroll
    for (int s = 0; s < 8; ++s)
        *(float4v*)(op + (size_t)s * ATT_FEAT) = acc[s];
}

// ---------------------------------------------------------------------------
extern "C" void kernel_launch(void* const* d_in, const int* in_sizes, int n_in,
                              void* d_out, int out_size, void* d_ws, size_t ws_size,
                              hipStream_t stream)
{
    const float* hidden = (const float*)d_in[0];
    const float* feats  = (const float*)d_in[1];
    const int*   mask   = (const int*)  d_in[2];
    const float* w_h    = (const float*)d_in[3];
    const float* w_u    = (const float*)d_in[4];
    const float* bvec   = (const float*)d_in[5];
    const float* wvec   = (const float*)d_in[6];

    float* out         = (float*)d_out;
    float* attn_out    = out;
    float* weights_out = out + (size_t)BATCH * SEQ * ATT_FEAT;

    // workspace layout
    float* Wh = (float*)d_ws;                                   // 1024x512 f32
    float* Uv = Wh + (size_t)BATCH * SEQ * EMBED;               // 3136x512 f32
    unsigned short* WhTh = (unsigned short*)(Uv + (size_t)BATCH * NKEY * EMBED);
    unsigned short* WhTl = WhTh + (size_t)EMBED * HIDDEN;       // [512][1024] bf16
    unsigned short* WuTh = WhTl + (size_t)EMBED * HIDDEN;
    unsigned short* WuTl = WuTh + (size_t)EMBED * ATT_FEAT;     // [512][2048] bf16

    // P1/P2: pre-split + transpose weights (one-shot, memory-bound)
    prep_split_transpose<<<dim3(HIDDEN / 32, EMBED / 32), 256, 0, stream>>>(
        w_h, WhTh, WhTl, HIDDEN, EMBED);
    prep_split_transpose<<<dim3(ATT_FEAT / 32, EMBED / 32), 256, 0, stream>>>(
        w_u, WuTh, WuTl, ATT_FEAT, EMBED);

    // K1: Wh = hidden @ w_h          grid 128 = 8*16
    gemm_mfma_ws<<<dim3((BATCH * SEQ / 64) * (EMBED / 64)), 256, 0, stream>>>(
        hidden, WhTh, WhTl, nullptr, Wh, EMBED, HIDDEN);

    // K2: Uv = feats @ w_u + b       grid 392 = 8*49
    gemm_mfma_ws<<<dim3((BATCH * NKEY / 64) * (EMBED / 64)), 256, 0, stream>>>(
        feats, WuTh, WuTl, bvec, Uv, EMBED, ATT_FEAT);

    // K3: scores (+mask) -> weights region of d_out
    scores_kernel<<<dim3((NKEY + 15) / 16, SEQ / 16, BATCH), 256, 0, stream>>>(
        Wh, Uv, wvec, mask, weights_out);

    // K4: softmax in place
    softmax_kernel<<<dim3(BATCH * SEQ), 64, 0, stream>>>(weights_out);

    // K5: attn_feats = weights @ feats
    attn_kernel<<<dim3(ATT_FEAT / 1024, SEQ / 8, BATCH), 256, 0, stream>>>(
        weights_out, feats, attn_out);
}